// Round 5
// baseline (191.565 us; speedup 1.0000x reference)
//
#include <hip/hip_runtime.h>
#include <math.h>

#define NTOT   12
#define DIM    4096      // 2^12
#define NB     1024      // batch
#define SPAD   4608      // phys(i) = i + 2*(i>>4); max 4095+510 = 4605

typedef float v2f __attribute__((ext_vector_type(2)));

// Fused (Ry*Rx) SU(2) gate on local bit G of a 16-amp register block.
// Scalar v_fma_f32 form; accumulation order matches the original pk version
// exactly (bit-identical output, validated R3/R4).
template<int G>
__device__ __forceinline__ void gate_sc(v2f (&x)[16],
                                        float cc, float cs, float ss, float sc) {
#pragma unroll
    for (int p = 0; p < 8; ++p) {
        const int j0 = ((p >> G) << (G + 1)) | (p & ((1 << G) - 1));
        const int j1 = j0 | (1 << G);
        const float x0r = x[j0].x, x0i = x[j0].y;
        const float x1r = x[j1].x, x1i = x[j1].y;

        float tr =  sc * x1i;                      // y0
        float ti = -sc * x1r;
        tr = __builtin_fmaf(-cs, x1r, tr);
        ti = __builtin_fmaf(-cs, x1i, ti);
        tr = __builtin_fmaf(-ss, x0i, tr);
        ti = __builtin_fmaf( ss, x0r, ti);
        tr = __builtin_fmaf( cc, x0r, tr);
        ti = __builtin_fmaf( cc, x0i, ti);

        float ur =  ss * x1i;                      // y1
        float ui = -ss * x1r;
        ur = __builtin_fmaf( cc, x1r, ur);
        ui = __builtin_fmaf( cc, x1i, ui);
        ur = __builtin_fmaf( sc, x0i, ur);
        ui = __builtin_fmaf(-sc, x0r, ui);
        ur = __builtin_fmaf( cs, x0r, ur);
        ui = __builtin_fmaf( cs, x0i, ui);

        x[j0] = (v2f){tr, ti};
        x[j1] = (v2f){ur, ui};
    }
}

// Apply the 4 gates of one partition-group (runtime gco base).
// gco[base+3]->G0, gco[base+2]->G1, gco[base+1]->G2, gco[base+0]->G3.
__device__ __forceinline__ void apply4(v2f (&x)[16], const float4* gco, int base) {
    float4 c;
    c = gco[base + 3]; gate_sc<0>(x, c.x, c.y, c.z, c.w);
    c = gco[base + 2]; gate_sc<1>(x, c.x, c.y, c.z, c.w);
    c = gco[base + 1]; gate_sc<2>(x, c.x, c.y, c.z, c.w);
    c = gco[base + 0]; gate_sc<3>(x, c.x, c.y, c.z, c.w);
}

// ROLLED palindrome schedule. Rounds 0-4 measured a ~50% VALU duty cap that is
// insensitive to instruction selection (pk vs scalar), ILP, and occupancy
// (1 vs 4 waves/SIMD) -- consistent with I-fetch streaming of the 25-50 KB
// fully-unrolled body (L1I = 32 KB, waves barrier-lockstepped into the same
// fetch window). This version re-rolls the 9 passes into one ~6-8 KB loop
// body: runtime (LDS base, stride), runtime gco base, CZ masks selected by
// v_cndmask between two precomputed register sets, and apply4 instantiated
// ONCE via an inner rep-loop. Schedule/barriers/layout/math identical to R0.
//   P0: C(l0)        P1: B(l0)      P2: A(l0)+CZa+A(l1)  P3: B(l1)
//   P4: C(l1)+CZc+C(l2)  P5: B(l2)  P6: A(l2)+CZa+A(l3)  P7: B(l3)
//   P8: C(l3)+CZc -> probs
__global__ __launch_bounds__(256, 4) void qddpm_kernel(
    const float* __restrict__ in_re,
    const float* __restrict__ in_im,
    const float* __restrict__ params,
    const float* __restrict__ uu,
    float* __restrict__ out)
{
    __shared__ v2f    S[SPAD];         // 36 KB, interleaved (re,im), padded layout
    __shared__ float4 gco[48];         // per-gate (cc, cs, ss, sc), g = lay*12+q
    __shared__ float  sprob[16];

    const int b = blockIdx.x;
    const int t = threadIdx.x;
    const float uval = uu[b];

    // per-thread bases (v2f element indices), phys(i) = i + 2*(i>>4)
    const int baseA = t + 2 * (t >> 4);            // A: S[baseA + 288*j], amp j*256+t
    const int baseB = (t >> 4) * 288 + (t & 15);   // B: S[baseB + 18*j],  amp (t>>4)*256+j*16+(t&15)
    const int baseC = t * 18;                      // C: S[baseC + j],     amp t*16+j

    v2f x[16];

    // ---- direct global -> registers, C-partition ----
    {
        const float4* re4 = (const float4*)(in_re + (size_t)b * DIM + t * 16);
        const float4* im4 = (const float4*)(in_im + (size_t)b * DIM + t * 16);
#pragma unroll
        for (int q = 0; q < 4; ++q) {
            const float4 vr = re4[q];
            const float4 vi = im4[q];
            x[4 * q + 0] = (v2f){vr.x, vi.x};
            x[4 * q + 1] = (v2f){vr.y, vi.y};
            x[4 * q + 2] = (v2f){vr.z, vi.z};
            x[4 * q + 3] = (v2f){vr.w, vi.w};
        }
    }
    if (t < 48) {                        // gate (lay = t/12, q = t%12)
        const int lay = t / 12, q = t - lay * 12;
        float c1, s1, c2, s2;
        sincosf(params[lay * 24 + q] * 0.5f, &s1, &c1);
        sincosf(params[lay * 24 + 12 + q] * 0.5f, &s2, &c2);
        gco[t] = make_float4(c1 * c2, c1 * s2, s1 * s2, s1 * c2); // (cc,cs,ss,sc)
    }

    // CZ sign-bit xor words for A- and C-partition views
    int swA[16], swC[16];
#pragma unroll
    for (int j = 0; j < 16; ++j) {
        const int iC = t * 16 + j;           // C-partition amp
        swC[j] = (__popc(iC & (iC >> 1) & 0x7FF) & 1) << 31;
        const int iA = j * 256 + t;          // A-partition amp
        swA[j] = (__popc(iA & (iA >> 1) & 0x7FF) & 1) << 31;
    }

    __syncthreads();                     // gco ready; x stays in registers

    static constexpr int B1_TBL[9] = {8, 4, 0, 16, 20, 28, 24, 40, 44};

#pragma clang loop unroll(disable)
    for (int pass = 0; pass < 9; ++pass) {
        const int  pat  = pass & 3;                    // 0:C 1:B 2:A 3:B
        const int  b1   = B1_TBL[pass];
        const bool cz   = (pass != 0) && ((pass & 1) == 0);   // 2,4,6,8
        const int  nrep = (cz && pass < 8) ? 2 : 1;           // doubled passes
        const bool isB  = (pass & 1) != 0;
        const int  stride = isB ? 18 : ((pat == 0) ? 1 : 288);
        const int  lb     = isB ? baseB : ((pat == 0) ? baseC : baseA);

        if (pass != 0) {
#pragma unroll
            for (int j = 0; j < 16; ++j) x[j] = S[lb + stride * j];
        }

#pragma clang loop unroll(disable)
        for (int rep = 0; rep < nrep; ++rep) {
            apply4(x, gco, b1 + rep * 12);
            if (rep == 0 && cz) {
                const bool useA = (pat == 2);
#pragma unroll
                for (int j = 0; j < 16; ++j) {
                    const unsigned m = useA ? (unsigned)swA[j] : (unsigned)swC[j];
                    x[j].x = __uint_as_float(__float_as_uint(x[j].x) ^ m);
                    x[j].y = __uint_as_float(__float_as_uint(x[j].y) ^ m);
                }
            }
        }

#pragma unroll
        for (int j = 0; j < 16; ++j) S[lb + stride * j] = x[j];
        __syncthreads();
    }

    // ---- probs: x holds post-CZ3 C-partition amps (i = t*16+j, outcome t>>4) ----
    {
        v2f acc2 = (v2f){0.0f, 0.0f};
#pragma unroll
        for (int j = 0; j < 16; ++j) acc2 += x[j] * x[j];
        float partial = acc2.x + acc2.y;
#pragma unroll
        for (int o = 8; o > 0; o >>= 1)
            partial += __shfl_down(partial, o, 16);
        if ((t & 15) == 0) sprob[t >> 4] = partial;
    }
    __syncthreads();

    // ---- redundant per-thread inverse-CDF sample + output [B, 256, 2] ----
    {
        float cdf[16];
        float a = 0.0f;
#pragma unroll
        for (int i = 0; i < 16; ++i) { a += sprob[i]; cdf[i] = a; }
        const float thresh = uval * a;
        int m = 0;
#pragma unroll
        for (int i = 15; i >= 0; --i) { if (cdf[i] >= thresh) m = i; }
        const float rn = 1.0f / sqrtf(sprob[m]);
        const v2f amp = S[baseA + 288 * m];     // phys(m*256 + t), A-pattern
        ((float2*)out)[(size_t)b * 256 + t] = make_float2(amp.x * rn, amp.y * rn);
    }
}

extern "C" void kernel_launch(void* const* d_in, const int* in_sizes, int n_in,
                              void* d_out, int out_size, void* d_ws, size_t ws_size,
                              hipStream_t stream) {
    const float* in_re  = (const float*)d_in[0];
    const float* in_im  = (const float*)d_in[1];
    const float* params = (const float*)d_in[2];
    const float* u      = (const float*)d_in[3];
    float* out = (float*)d_out;
    qddpm_kernel<<<NB, 256, 0, stream>>>(in_re, in_im, params, u, out);
}

// Round 6
// 115.265 us; speedup vs baseline: 1.6619x; 1.6619x over previous
//
#include <hip/hip_runtime.h>
#include <math.h>

#define NTOT   12
#define DIM    4096      // 2^12
#define NB     1024      // batch

typedef float v2f __attribute__((ext_vector_type(2)));

// Fused (Ry*Rx) SU(2) gate on local bit G of a 16-amp register block, complex
// interleaved (lo=re, hi=im). Coefficients packed: P1=(cc,cs), P2=(ss,sc).
// v_pk form: half the instruction count of scalar at equal ALU cycles
// (R0 vs R4: 44.8 vs 48.5 us) -> keep pk for fetch bandwidth.
template<int G>
__device__ __forceinline__ void gate_pk(v2f (&x)[16], v2f P1, v2f P2) {
#pragma unroll
    for (int p = 0; p < 8; ++p) {
        const int j0 = ((p >> G) << (G + 1)) | (p & ((1 << G) - 1));
        const int j1 = j0 | (1 << G);
        const v2f x0 = x[j0], x1 = x[j1];
        v2f t, u;
        asm("v_pk_mul_f32 %0, %1, %2 op_sel:[1,1] op_sel_hi:[1,0] neg_hi:[1,0]"
            : "=v"(t) : "v"(P2), "v"(x1));
        asm("v_pk_fma_f32 %0, %1, %2, %0 op_sel:[1,0,0] op_sel_hi:[1,1,1] neg_lo:[1,0,0] neg_hi:[1,0,0]"
            : "+v"(t) : "v"(P1), "v"(x1));
        asm("v_pk_fma_f32 %0, %1, %2, %0 op_sel:[0,1,0] op_sel_hi:[0,0,1] neg_lo:[1,0,0]"
            : "+v"(t) : "v"(P2), "v"(x0));
        asm("v_pk_fma_f32 %0, %1, %2, %0 op_sel:[0,0,0] op_sel_hi:[0,1,1]"
            : "+v"(t) : "v"(P1), "v"(x0));
        asm("v_pk_mul_f32 %0, %1, %2 op_sel:[0,1] op_sel_hi:[0,0] neg_hi:[1,0]"
            : "=v"(u) : "v"(P2), "v"(x1));
        asm("v_pk_fma_f32 %0, %1, %2, %0 op_sel:[0,0,0] op_sel_hi:[0,1,1]"
            : "+v"(u) : "v"(P1), "v"(x1));
        asm("v_pk_fma_f32 %0, %1, %2, %0 op_sel:[1,1,0] op_sel_hi:[1,0,1] neg_hi:[1,0,0]"
            : "+v"(u) : "v"(P2), "v"(x0));
        asm("v_pk_fma_f32 %0, %1, %2, %0 op_sel:[1,0,0] op_sel_hi:[1,1,1]"
            : "+v"(u) : "v"(P1), "v"(x0));
        x[j0] = t; x[j1] = u;
    }
}

__device__ __forceinline__ float rl(float v, int l) {
    return __int_as_float(__builtin_amdgcn_readlane(__float_as_int(v), l));
}

// Apply the 4 gates of one partition-group; coeffs broadcast from wave lanes
// base+3 -> G0 ... base+0 -> G3 (no LDS table: readlane from gv* registers).
__device__ __forceinline__ void apply4(v2f (&x)[16],
                                       float gv0, float gv1, float gv2, float gv3,
                                       int base) {
    v2f P1, P2;
#define LDCO(GL) \
    P1.x = rl(gv0, (GL)); P1.y = rl(gv1, (GL)); \
    P2.x = rl(gv2, (GL)); P2.y = rl(gv3, (GL));
    LDCO(base + 3); gate_pk<0>(x, P1, P2);
    LDCO(base + 2); gate_pk<1>(x, P1, P2);
    LDCO(base + 1); gate_pk<2>(x, P1, P2);
    LDCO(base + 0); gate_pk<3>(x, P1, P2);
#undef LDCO
}

// CZ diagonal: flip sign bits via precomputed xor words (0 or 0x80000000).
__device__ __forceinline__ void applyCZ(v2f (&x)[16], const int (&sw)[16]) {
#pragma unroll
    for (int j = 0; j < 16; ++j) {
        x[j].x = __uint_as_float(__float_as_uint(x[j].x) ^ sw[j]);
        x[j].y = __uint_as_float(__float_as_uint(x[j].y) ^ sw[j]);
    }
}

// ZERO-PAD swizzled layout: phys(i) = i ^ ((i>>4) & 14)  (xor bits[3:1] with
// bits[7:5]; involution, pair-preserving so C-partition keeps b128).
//   C (i=t*16+j):        phys = t*16 + (j ^ (t&14))           -> conflict-free b128
//   B (i=(t>>4)*256+j*16+(t&15)): phys = .. + ((t&15)^(j&14)) -> 4 lanes/bank-pair
//   A (i=j*256+t):       phys = j*256 + (t ^ ((t>>4)&14))     -> 4 lanes/bank-pair
// S = exactly 32768 B (no gco/sprob in LDS) -> 5 blocks/CU = 20 waves/CU,
// up from R0's 4 blocks (36.9 KB padded). gco lives in wave registers
// (readlane); probs are recomputed per-wave from a full-state LDS scan.
// Palindrome schedule (9 passes, 9 barriers):
//   C0|B0|A0+CZ+A1|B1|C1+CZ+C2|B2|A2+CZ+A3|B3|C3+CZ -> probs
__global__ __launch_bounds__(256, 5) void qddpm_kernel(
    const float* __restrict__ in_re,
    const float* __restrict__ in_im,
    const float* __restrict__ params,
    const float* __restrict__ uu,
    float* __restrict__ out)
{
    __shared__ v2f S[DIM];               // exactly 32 KB

    const int b    = blockIdx.x;
    const int t    = threadIdx.x;
    const int lane = t & 63;
    const float uval = uu[b];

    // swizzled per-thread bases (v2f element indices)
    const int hsC   = (t >> 1) & 7;                 // C: float4 slot = q ^ hsC
    const int baseC = t * 16;
    const int tA    = t ^ ((t >> 4) & 14);          // A: S[j*256 + tA]
    const int baseB = (t >> 4) * 256 + (t & 15);    // B: S[baseB + j*16 + xorB(j)]

    v2f x[16];

    // ---- direct global -> registers, C-partition ----
    {
        const float4* re4 = (const float4*)(in_re + (size_t)b * DIM + t * 16);
        const float4* im4 = (const float4*)(in_im + (size_t)b * DIM + t * 16);
#pragma unroll
        for (int q = 0; q < 4; ++q) {
            const float4 vr = re4[q];
            const float4 vi = im4[q];
            x[4 * q + 0] = (v2f){vr.x, vi.x};
            x[4 * q + 1] = (v2f){vr.y, vi.y};
            x[4 * q + 2] = (v2f){vr.z, vi.z};
            x[4 * q + 3] = (v2f){vr.w, vi.w};
        }
    }

    // ---- per-wave gate coefficients: lane g (g<48) holds gate g's (cc,cs,ss,sc)
    float gv0 = 0.f, gv1 = 0.f, gv2 = 0.f, gv3 = 0.f;
    if (lane < 48) {
        const int lay = lane / 12, q = lane - lay * 12;
        float c1, s1, c2, s2;
        sincosf(params[lay * 24 + q] * 0.5f, &s1, &c1);
        sincosf(params[lay * 24 + 12 + q] * 0.5f, &s2, &c2);
        gv0 = c1 * c2; gv1 = c1 * s2; gv2 = s1 * s2; gv3 = s1 * c2;
    }

    // CZ sign-bit xor words for C- and A-partition views (logical amp indices)
    int swA[16], swC[16];
#pragma unroll
    for (int j = 0; j < 16; ++j) {
        const int iC = t * 16 + j;
        swC[j] = (__popc(iC & (iC >> 1) & 0x7FF) & 1) << 31;
        const int iA = j * 256 + t;
        swA[j] = (__popc(iA & (iA >> 1) & 0x7FF) & 1) << 31;
    }

    // LDS access helpers (macros keep full unroll / constant indices)
#define C_WRITE() { float4* dst = (float4*)(S + baseC); \
    _Pragma("unroll") for (int q = 0; q < 8; ++q) \
        dst[q ^ hsC] = make_float4(x[2*q].x, x[2*q].y, x[2*q+1].x, x[2*q+1].y); }
#define C_READ() { const float4* src = (const float4*)(S + baseC); \
    _Pragma("unroll") for (int q = 0; q < 8; ++q) { const float4 v = src[q ^ hsC]; \
        x[2*q] = (v2f){v.x, v.y}; x[2*q+1] = (v2f){v.z, v.w}; } }
#define B_IDX(j) (baseB + (j) * 16 + (((t & 15) ^ ((j) & 14)) - (t & 15)))
#define B_READ()  { _Pragma("unroll") for (int j = 0; j < 16; ++j) x[j] = S[B_IDX(j)]; }
#define B_WRITE() { _Pragma("unroll") for (int j = 0; j < 16; ++j) S[B_IDX(j)] = x[j]; }
#define A_READ()  { _Pragma("unroll") for (int j = 0; j < 16; ++j) x[j] = S[j * 256 + tA]; }
#define A_WRITE() { _Pragma("unroll") for (int j = 0; j < 16; ++j) S[j * 256 + tA] = x[j]; }

    // ---- P1: C gates layer0 (q8..q11) ----
    apply4(x, gv0, gv1, gv2, gv3, 0 * 12 + 8);
    C_WRITE();
    __syncthreads();                     // (1)

    // ---- P2: B gates layer0 ----
    B_READ();
    apply4(x, gv0, gv1, gv2, gv3, 0 * 12 + 4);
    B_WRITE();
    __syncthreads();                     // (2)

    // ---- P3: A layer0 + CZ0 + A layer1 ----
    A_READ();
    apply4(x, gv0, gv1, gv2, gv3, 0 * 12 + 0);
    applyCZ(x, swA);
    apply4(x, gv0, gv1, gv2, gv3, 1 * 12 + 0);
    A_WRITE();
    __syncthreads();                     // (3)

    // ---- P4: B layer1 ----
    B_READ();
    apply4(x, gv0, gv1, gv2, gv3, 1 * 12 + 4);
    B_WRITE();
    __syncthreads();                     // (4)

    // ---- P5: C layer1 + CZ1 + C layer2 ----
    C_READ();
    apply4(x, gv0, gv1, gv2, gv3, 1 * 12 + 8);
    applyCZ(x, swC);
    apply4(x, gv0, gv1, gv2, gv3, 2 * 12 + 8);
    C_WRITE();
    __syncthreads();                     // (5)

    // ---- P6: B layer2 ----
    B_READ();
    apply4(x, gv0, gv1, gv2, gv3, 2 * 12 + 4);
    B_WRITE();
    __syncthreads();                     // (6)

    // ---- P7: A layer2 + CZ2 + A layer3 ----
    A_READ();
    apply4(x, gv0, gv1, gv2, gv3, 2 * 12 + 0);
    applyCZ(x, swA);
    apply4(x, gv0, gv1, gv2, gv3, 3 * 12 + 0);
    A_WRITE();
    __syncthreads();                     // (7)

    // ---- P8: B layer3 ----
    B_READ();
    apply4(x, gv0, gv1, gv2, gv3, 3 * 12 + 4);
    B_WRITE();
    __syncthreads();                     // (8)

    // ---- P9: C layer3 + CZ3 ----
    C_READ();
    apply4(x, gv0, gv1, gv2, gv3, 3 * 12 + 8);
    applyCZ(x, swC);
    C_WRITE();
    __syncthreads();                     // (9) full final state visible

    // ---- probs: each wave redundantly scans the whole state from LDS ----
    // lane covers logical amps [lane*64, lane*64+64) -> group g = lane>>2.
    // b128 slot order per lane is rotated (qq = q ^ (lane&31)) to spread banks.
    float partial = 0.f;
#pragma unroll
    for (int q = 0; q < 32; ++q) {
        const int qq = q ^ (lane & 31);
        const int X  = (lane * 4 + (qq >> 3)) & 14;          // swizzle field
        const float4 v = ((const float4*)S)[lane * 32 + (qq ^ (X >> 1))];
        partial = __builtin_fmaf(v.x, v.x,
                  __builtin_fmaf(v.y, v.y,
                  __builtin_fmaf(v.z, v.z,
                  __builtin_fmaf(v.w, v.w, partial))));
    }
    partial += __shfl_xor(partial, 1);
    partial += __shfl_xor(partial, 2);          // lanes 4g..4g+3: group-g sum

    float pr[16];
#pragma unroll
    for (int g = 0; g < 16; ++g) pr[g] = __shfl(partial, g * 4);

    // ---- redundant per-thread inverse-CDF sample + output [B, 256, 2] ----
    float cdf[16];
    float a = 0.f;
#pragma unroll
    for (int g = 0; g < 16; ++g) { a += pr[g]; cdf[g] = a; }
    const float thresh = uval * a;
    int m = 0;
#pragma unroll
    for (int g = 15; g >= 0; --g) { if (cdf[g] >= thresh) m = g; }
    float pm = pr[0];
#pragma unroll
    for (int g = 1; g < 16; ++g) { if (m == g) pm = pr[g]; }
    const float rn = 1.0f / sqrtf(pm);

    const v2f amp = S[m * 256 + tA];            // A-pattern read of outcome m
    ((float2*)out)[(size_t)b * 256 + t] = make_float2(amp.x * rn, amp.y * rn);
}

extern "C" void kernel_launch(void* const* d_in, const int* in_sizes, int n_in,
                              void* d_out, int out_size, void* d_ws, size_t ws_size,
                              hipStream_t stream) {
    const float* in_re  = (const float*)d_in[0];
    const float* in_im  = (const float*)d_in[1];
    const float* params = (const float*)d_in[2];
    const float* u      = (const float*)d_in[3];
    float* out = (float*)d_out;
    qddpm_kernel<<<NB, 256, 0, stream>>>(in_re, in_im, params, u, out);
}

// Round 7
// 113.137 us; speedup vs baseline: 1.6932x; 1.0188x over previous
//
#include <hip/hip_runtime.h>
#include <math.h>

#define NTOT   12
#define DIM    4096      // 2^12 amplitudes per item
#define NB     1024      // batch
#define NBLK   (NB / 2)  // 2 items per block

typedef float v2f __attribute__((ext_vector_type(2)));

// Fused (Ry*Rx) SU(2) gate on local bit G of a 16-amp register block, complex
// interleaved (lo=re, hi=im). Coefficients packed: P1=(cc,cs), P2=(ss,sc).
template<int G>
__device__ __forceinline__ void gate_pk(v2f (&x)[16], v2f P1, v2f P2) {
#pragma unroll
    for (int p = 0; p < 8; ++p) {
        const int j0 = ((p >> G) << (G + 1)) | (p & ((1 << G) - 1));
        const int j1 = j0 | (1 << G);
        const v2f x0 = x[j0], x1 = x[j1];
        v2f t, u;
        asm("v_pk_mul_f32 %0, %1, %2 op_sel:[1,1] op_sel_hi:[1,0] neg_hi:[1,0]"
            : "=v"(t) : "v"(P2), "v"(x1));
        asm("v_pk_fma_f32 %0, %1, %2, %0 op_sel:[1,0,0] op_sel_hi:[1,1,1] neg_lo:[1,0,0] neg_hi:[1,0,0]"
            : "+v"(t) : "v"(P1), "v"(x1));
        asm("v_pk_fma_f32 %0, %1, %2, %0 op_sel:[0,1,0] op_sel_hi:[0,0,1] neg_lo:[1,0,0]"
            : "+v"(t) : "v"(P2), "v"(x0));
        asm("v_pk_fma_f32 %0, %1, %2, %0 op_sel:[0,0,0] op_sel_hi:[0,1,1]"
            : "+v"(t) : "v"(P1), "v"(x0));
        asm("v_pk_mul_f32 %0, %1, %2 op_sel:[0,1] op_sel_hi:[0,0] neg_hi:[1,0]"
            : "=v"(u) : "v"(P2), "v"(x1));
        asm("v_pk_fma_f32 %0, %1, %2, %0 op_sel:[0,0,0] op_sel_hi:[0,1,1]"
            : "+v"(u) : "v"(P1), "v"(x1));
        asm("v_pk_fma_f32 %0, %1, %2, %0 op_sel:[1,1,0] op_sel_hi:[1,0,1] neg_hi:[1,0,0]"
            : "+v"(u) : "v"(P2), "v"(x0));
        asm("v_pk_fma_f32 %0, %1, %2, %0 op_sel:[1,0,0] op_sel_hi:[1,1,1]"
            : "+v"(u) : "v"(P1), "v"(x0));
        x[j0] = t; x[j1] = u;
    }
}

__device__ __forceinline__ float rl(float v, int l) {
    return __int_as_float(__builtin_amdgcn_readlane(__float_as_int(v), l));
}

// Apply the 4 gates of one partition-group; coeffs broadcast from wave lanes
// base+3 -> G0 ... base+0 -> G3 (readlane from gv* registers; params are
// shared across the batch, so one coeff set serves both items).
__device__ __forceinline__ void apply4(v2f (&x)[16],
                                       float gv0, float gv1, float gv2, float gv3,
                                       int base) {
    v2f P1, P2;
#define LDCO(GL) \
    P1.x = rl(gv0, (GL)); P1.y = rl(gv1, (GL)); \
    P2.x = rl(gv2, (GL)); P2.y = rl(gv3, (GL));
    LDCO(base + 3); gate_pk<0>(x, P1, P2);
    LDCO(base + 2); gate_pk<1>(x, P1, P2);
    LDCO(base + 1); gate_pk<2>(x, P1, P2);
    LDCO(base + 0); gate_pk<3>(x, P1, P2);
#undef LDCO
}

__device__ __forceinline__ void applyCZ(v2f (&x)[16], const int (&sw)[16]) {
#pragma unroll
    for (int j = 0; j < 16; ++j) {
        x[j].x = __uint_as_float(__float_as_uint(x[j].x) ^ sw[j]);
        x[j].y = __uint_as_float(__float_as_uint(x[j].y) ^ sw[j]);
    }
}

// --- R6 zero-pad swizzled layout (validated): phys(i) = i ^ ((i>>4)&14) ---
__device__ __forceinline__ void c_write(v2f* S, const v2f (&x)[16], int t) {
    float4* dst = (float4*)(S + t * 16);
    const int hsC = (t >> 1) & 7;
#pragma unroll
    for (int q = 0; q < 8; ++q)
        dst[q ^ hsC] = make_float4(x[2*q].x, x[2*q].y, x[2*q+1].x, x[2*q+1].y);
}
__device__ __forceinline__ void c_read(const v2f* S, v2f (&x)[16], int t) {
    const float4* src = (const float4*)(S + t * 16);
    const int hsC = (t >> 1) & 7;
#pragma unroll
    for (int q = 0; q < 8; ++q) {
        const float4 v = src[q ^ hsC];
        x[2*q]   = (v2f){v.x, v.y};
        x[2*q+1] = (v2f){v.z, v.w};
    }
}
__device__ __forceinline__ void b_read(const v2f* S, v2f (&x)[16], int t) {
#pragma unroll
    for (int j = 0; j < 16; ++j)
        x[j] = S[(t >> 4) * 256 + j * 16 + ((t & 15) ^ (j & 14))];
}
__device__ __forceinline__ void b_write(v2f* S, const v2f (&x)[16], int t) {
#pragma unroll
    for (int j = 0; j < 16; ++j)
        S[(t >> 4) * 256 + j * 16 + ((t & 15) ^ (j & 14))] = x[j];
}
__device__ __forceinline__ void a_read(const v2f* S, v2f (&x)[16], int tA) {
#pragma unroll
    for (int j = 0; j < 16; ++j) x[j] = S[j * 256 + tA];
}
__device__ __forceinline__ void a_write(v2f* S, const v2f (&x)[16], int tA) {
#pragma unroll
    for (int j = 0; j < 16; ++j) S[j * 256 + tA] = x[j];
}

// TWO ITEMS PER BLOCK, software-pipelined. Rounds 0-6 established: VALU busy
// cycles always match theory (~49k pk/SIMD); the ~50% idle is phase-locked
// LDS/barrier/prologue stalls (all co-resident blocks run identical code in
// lockstep, so every stall hits every wave of the CU simultaneously).
// Pipelining item B behind item A inside one wave gives every LDS wait an
// adjacent independent gate burst: issue readsA, issue readsB, gatesA (B's
// reads land underneath), writeA, gatesB (A's writes drain), writeB, ONE bar.
// Barriers/item: 10 -> 5. Prologue: B's HBM load hides under A's pass 1.
// Epilogue: final pass keeps the state in registers (threads with t>>4 == m
// own outcome m's 256 amps) -> no final LDS write; the 16 group-probs reuse
// the then-dead state buffer.
__global__ __launch_bounds__(256, 2) void qddpm_kernel(
    const float* __restrict__ in_re,
    const float* __restrict__ in_im,
    const float* __restrict__ params,
    const float* __restrict__ uu,
    float* __restrict__ out)
{
    __shared__ v2f SA[DIM];              // 32 KB
    __shared__ v2f SB[DIM];              // 32 KB  (total = 64 KB static)

    const int blk  = blockIdx.x;
    const int t    = threadIdx.x;
    const int lane = t & 63;
    const int bA   = 2 * blk;
    const int bB   = 2 * blk + 1;
    const int tA   = t ^ ((t >> 4) & 14);        // A-pattern swizzled thread index

    const float uvalA = uu[bA];
    const float uvalB = uu[bB];

    v2f xA[16], xB[16];

    // ---- global -> registers, C-partition, both items (A first, B behind) ----
    {
        const float4* reA = (const float4*)(in_re + (size_t)bA * DIM + t * 16);
        const float4* imA = (const float4*)(in_im + (size_t)bA * DIM + t * 16);
        const float4* reB = (const float4*)(in_re + (size_t)bB * DIM + t * 16);
        const float4* imB = (const float4*)(in_im + (size_t)bB * DIM + t * 16);
#pragma unroll
        for (int q = 0; q < 4; ++q) {
            const float4 vr = reA[q];
            const float4 vi = imA[q];
            xA[4*q+0] = (v2f){vr.x, vi.x};
            xA[4*q+1] = (v2f){vr.y, vi.y};
            xA[4*q+2] = (v2f){vr.z, vi.z};
            xA[4*q+3] = (v2f){vr.w, vi.w};
        }
#pragma unroll
        for (int q = 0; q < 4; ++q) {
            const float4 vr = reB[q];
            const float4 vi = imB[q];
            xB[4*q+0] = (v2f){vr.x, vi.x};
            xB[4*q+1] = (v2f){vr.y, vi.y};
            xB[4*q+2] = (v2f){vr.z, vi.z};
            xB[4*q+3] = (v2f){vr.w, vi.w};
        }
    }

    // ---- per-wave gate coefficients (shared by both items) ----
    float gv0 = 0.f, gv1 = 0.f, gv2 = 0.f, gv3 = 0.f;
    if (lane < 48) {
        const int lay = lane / 12, q = lane - lay * 12;
        float c1, s1, c2, s2;
        sincosf(params[lay * 24 + q] * 0.5f, &s1, &c1);
        sincosf(params[lay * 24 + 12 + q] * 0.5f, &s2, &c2);
        gv0 = c1 * c2; gv1 = c1 * s2; gv2 = s1 * s2; gv3 = s1 * c2;
    }

    // ---- CZ sign-bit xor words (depend only on t: shared by both items) ----
    int swA[16], swC[16];
#pragma unroll
    for (int j = 0; j < 16; ++j) {
        const int iC = t * 16 + j;
        swC[j] = (__popc(iC & (iC >> 1) & 0x7FF) & 1) << 31;
        const int iA = j * 256 + t;
        swA[j] = (__popc(iA & (iA >> 1) & 0x7FF) & 1) << 31;
    }

    // ---- P1: C gates layer0 (q8..q11); B's loads land under A's gates ----
    apply4(xA, gv0, gv1, gv2, gv3, 0 * 12 + 8);
    c_write(SA, xA, t);
    apply4(xB, gv0, gv1, gv2, gv3, 0 * 12 + 8);
    c_write(SB, xB, t);
    __syncthreads();                     // (1)

    // ---- P2: B gates layer0 ----
    b_read(SA, xA, t);
    b_read(SB, xB, t);
    apply4(xA, gv0, gv1, gv2, gv3, 0 * 12 + 4);
    b_write(SA, xA, t);
    apply4(xB, gv0, gv1, gv2, gv3, 0 * 12 + 4);
    b_write(SB, xB, t);
    __syncthreads();                     // (2)

    // ---- P3: A layer0 + CZ0 + A layer1 ----
    a_read(SA, xA, tA);
    a_read(SB, xB, tA);
    apply4(xA, gv0, gv1, gv2, gv3, 0 * 12 + 0);
    applyCZ(xA, swA);
    apply4(xA, gv0, gv1, gv2, gv3, 1 * 12 + 0);
    a_write(SA, xA, tA);
    apply4(xB, gv0, gv1, gv2, gv3, 0 * 12 + 0);
    applyCZ(xB, swA);
    apply4(xB, gv0, gv1, gv2, gv3, 1 * 12 + 0);
    a_write(SB, xB, tA);
    __syncthreads();                     // (3)

    // ---- P4: B layer1 ----
    b_read(SA, xA, t);
    b_read(SB, xB, t);
    apply4(xA, gv0, gv1, gv2, gv3, 1 * 12 + 4);
    b_write(SA, xA, t);
    apply4(xB, gv0, gv1, gv2, gv3, 1 * 12 + 4);
    b_write(SB, xB, t);
    __syncthreads();                     // (4)

    // ---- P5: C layer1 + CZ1 + C layer2 ----
    c_read(SA, xA, t);
    c_read(SB, xB, t);
    apply4(xA, gv0, gv1, gv2, gv3, 1 * 12 + 8);
    applyCZ(xA, swC);
    apply4(xA, gv0, gv1, gv2, gv3, 2 * 12 + 8);
    c_write(SA, xA, t);
    apply4(xB, gv0, gv1, gv2, gv3, 1 * 12 + 8);
    applyCZ(xB, swC);
    apply4(xB, gv0, gv1, gv2, gv3, 2 * 12 + 8);
    c_write(SB, xB, t);
    __syncthreads();                     // (5)

    // ---- P6: B layer2 ----
    b_read(SA, xA, t);
    b_read(SB, xB, t);
    apply4(xA, gv0, gv1, gv2, gv3, 2 * 12 + 4);
    b_write(SA, xA, t);
    apply4(xB, gv0, gv1, gv2, gv3, 2 * 12 + 4);
    b_write(SB, xB, t);
    __syncthreads();                     // (6)

    // ---- P7: A layer2 + CZ2 + A layer3 ----
    a_read(SA, xA, tA);
    a_read(SB, xB, tA);
    apply4(xA, gv0, gv1, gv2, gv3, 2 * 12 + 0);
    applyCZ(xA, swA);
    apply4(xA, gv0, gv1, gv2, gv3, 3 * 12 + 0);
    a_write(SA, xA, tA);
    apply4(xB, gv0, gv1, gv2, gv3, 2 * 12 + 0);
    applyCZ(xB, swA);
    apply4(xB, gv0, gv1, gv2, gv3, 3 * 12 + 0);
    a_write(SB, xB, tA);
    __syncthreads();                     // (7)

    // ---- P8: B layer3 ----
    b_read(SA, xA, t);
    b_read(SB, xB, t);
    apply4(xA, gv0, gv1, gv2, gv3, 3 * 12 + 4);
    b_write(SA, xA, t);
    apply4(xB, gv0, gv1, gv2, gv3, 3 * 12 + 4);
    b_write(SB, xB, t);
    __syncthreads();                     // (8)

    // ---- P9: C layer3 + CZ3; state stays in registers ----
    c_read(SA, xA, t);
    c_read(SB, xB, t);
    __syncthreads();                     // (9) all reads done -> buffers dead

    apply4(xA, gv0, gv1, gv2, gv3, 3 * 12 + 8);
    applyCZ(xA, swC);
    apply4(xB, gv0, gv1, gv2, gv3, 3 * 12 + 8);
    applyCZ(xB, swC);

    // probs: thread t's 16 amps (i = t*16+j) all belong to outcome t>>4
    float pA, pB;
    {
        v2f accA = (v2f){0.f, 0.f}, accB = (v2f){0.f, 0.f};
#pragma unroll
        for (int j = 0; j < 16; ++j) { accA += xA[j] * xA[j]; accB += xB[j] * xB[j]; }
        pA = accA.x + accA.y;
        pB = accB.x + accB.y;
#pragma unroll
        for (int o = 8; o > 0; o >>= 1) {
            pA += __shfl_down(pA, o, 16);
            pB += __shfl_down(pB, o, 16);
        }
    }
    if ((t & 15) == 0) {                 // group sums into the dead buffers
        ((float*)SA)[t >> 4] = pA;
        ((float*)SB)[t >> 4] = pB;
    }
    __syncthreads();                     // (10)

    // ---- redundant per-thread inverse-CDF sample + register-direct output ----
    {
        const float* prA = (const float*)SA;
        const float* prB = (const float*)SB;
        float cdfA[16], cdfB[16];
        float aA = 0.f, aB = 0.f;
#pragma unroll
        for (int i = 0; i < 16; ++i) {
            aA += prA[i]; cdfA[i] = aA;
            aB += prB[i]; cdfB[i] = aB;
        }
        const float thA = uvalA * aA;
        const float thB = uvalB * aB;
        int mA = 0, mB = 0;
#pragma unroll
        for (int i = 15; i >= 0; --i) {
            if (cdfA[i] >= thA) mA = i;
            if (cdfB[i] >= thB) mB = i;
        }
        const float rnA = 1.0f / sqrtf(prA[mA]);
        const float rnB = 1.0f / sqrtf(prB[mB]);

        // threads with t>>4 == m hold outcome m's 256 amps in registers
        if ((t >> 4) == mA) {
            float4* o = (float4*)out + (size_t)bA * 128 + (t & 15) * 8;
#pragma unroll
            for (int q = 0; q < 8; ++q)
                o[q] = make_float4(xA[2*q].x * rnA, xA[2*q].y * rnA,
                                   xA[2*q+1].x * rnA, xA[2*q+1].y * rnA);
        }
        if ((t >> 4) == mB) {
            float4* o = (float4*)out + (size_t)bB * 128 + (t & 15) * 8;
#pragma unroll
            for (int q = 0; q < 8; ++q)
                o[q] = make_float4(xB[2*q].x * rnB, xB[2*q].y * rnB,
                                   xB[2*q+1].x * rnB, xB[2*q+1].y * rnB);
        }
    }
}

extern "C" void kernel_launch(void* const* d_in, const int* in_sizes, int n_in,
                              void* d_out, int out_size, void* d_ws, size_t ws_size,
                              hipStream_t stream) {
    const float* in_re  = (const float*)d_in[0];
    const float* in_im  = (const float*)d_in[1];
    const float* params = (const float*)d_in[2];
    const float* u      = (const float*)d_in[3];
    float* out = (float*)d_out;
    qddpm_kernel<<<NBLK, 256, 0, stream>>>(in_re, in_im, params, u, out);
}

// Round 8
// 108.564 us; speedup vs baseline: 1.7645x; 1.0421x over previous
//
#include <hip/hip_runtime.h>
#include <math.h>

#define NTOT   12
#define DIM    4096      // 2^12
#define NB     1024      // batch
#define SPAD   4608      // phys(i) = i + 2*(i>>4); max 4095+510 = 4605

typedef float v2f __attribute__((ext_vector_type(2)));

// Fused (Ry*Rx) SU(2) gate on local bit G of a 16-amp register block, complex
// interleaved (lo=re, hi=im). Coefficients packed: P1=(cc,cs), P2=(ss,sc).
// pk form: half the I-footprint of scalar at equal ALU cycles (R0 vs R4).
template<int G>
__device__ __forceinline__ void gate_pk(v2f (&x)[16], v2f P1, v2f P2) {
#pragma unroll
    for (int p = 0; p < 8; ++p) {
        const int j0 = ((p >> G) << (G + 1)) | (p & ((1 << G) - 1));
        const int j1 = j0 | (1 << G);
        const v2f x0 = x[j0], x1 = x[j1];
        v2f t, u;
        asm("v_pk_mul_f32 %0, %1, %2 op_sel:[1,1] op_sel_hi:[1,0] neg_hi:[1,0]"
            : "=v"(t) : "v"(P2), "v"(x1));
        asm("v_pk_fma_f32 %0, %1, %2, %0 op_sel:[1,0,0] op_sel_hi:[1,1,1] neg_lo:[1,0,0] neg_hi:[1,0,0]"
            : "+v"(t) : "v"(P1), "v"(x1));
        asm("v_pk_fma_f32 %0, %1, %2, %0 op_sel:[0,1,0] op_sel_hi:[0,0,1] neg_lo:[1,0,0]"
            : "+v"(t) : "v"(P2), "v"(x0));
        asm("v_pk_fma_f32 %0, %1, %2, %0 op_sel:[0,0,0] op_sel_hi:[0,1,1]"
            : "+v"(t) : "v"(P1), "v"(x0));
        asm("v_pk_mul_f32 %0, %1, %2 op_sel:[0,1] op_sel_hi:[0,0] neg_hi:[1,0]"
            : "=v"(u) : "v"(P2), "v"(x1));
        asm("v_pk_fma_f32 %0, %1, %2, %0 op_sel:[0,0,0] op_sel_hi:[0,1,1]"
            : "+v"(u) : "v"(P1), "v"(x1));
        asm("v_pk_fma_f32 %0, %1, %2, %0 op_sel:[1,1,0] op_sel_hi:[1,0,1] neg_hi:[1,0,0]"
            : "+v"(u) : "v"(P2), "v"(x0));
        asm("v_pk_fma_f32 %0, %1, %2, %0 op_sel:[1,0,0] op_sel_hi:[1,1,1]"
            : "+v"(u) : "v"(P1), "v"(x0));
        x[j0] = t; x[j1] = u;
    }
}

__device__ __forceinline__ float rl(float v, int l) {
    return __int_as_float(__builtin_amdgcn_readlane(__float_as_int(v), l));
}

// Apply the 4 gates of one partition-group; coeffs broadcast from wave lanes
// base+3 -> G0 ... base+0 -> G3 (readlane from gv* registers; no LDS table,
// no init barrier). Validated R6/R7.
__device__ __forceinline__ void apply4(v2f (&x)[16],
                                       float gv0, float gv1, float gv2, float gv3,
                                       int base) {
    v2f P1, P2;
#define LDCO(GL) \
    P1.x = rl(gv0, (GL)); P1.y = rl(gv1, (GL)); \
    P2.x = rl(gv2, (GL)); P2.y = rl(gv3, (GL));
    LDCO(base + 3); gate_pk<0>(x, P1, P2);
    LDCO(base + 2); gate_pk<1>(x, P1, P2);
    LDCO(base + 1); gate_pk<2>(x, P1, P2);
    LDCO(base + 0); gate_pk<3>(x, P1, P2);
#undef LDCO
}

// CZ diagonal: flip sign bits via precomputed xor words (0 or 0x80000000).
__device__ __forceinline__ void applyCZ(v2f (&x)[16], const int (&sw)[16]) {
#pragma unroll
    for (int j = 0; j < 16; ++j) {
        x[j].x = __uint_as_float(__float_as_uint(x[j].x) ^ sw[j]);
        x[j].y = __uint_as_float(__float_as_uint(x[j].y) ^ sw[j]);
    }
}

#define WAVEWAIT() asm volatile("s_waitcnt lgkmcnt(0)" ::: "memory")

// R0 padded layout (validated): phys(i) = i + 2*(i>>4).
// BARRIER-MINIMIZED palindrome. Key observation (new this round): the C<->B
// exchanges are 16-LANE-LOCAL -- C-amp t*16+j belongs in B-partition to thread
// (t>>4)*16 + j, i.e. the same quarter-wave (threads 16g..16g+15 always lie in
// one 64-lane wave). Only B<->A exchanges cross waves. So 5 of R0's 9
// inter-pass barriers become wave-private s_waitcnt lgkmcnt(0) (the rounds-1-3
// correctness pattern), while KEEPING 4 blocks/CU (R7 halved barriers but paid
// occupancy: 47.5 vs 44.8 us).
//   C0 |wait| B0 |BAR1| A0+CZ+A1 |BAR2| B1 |wait| C1+CZ+C2 |wait| B2 |BAR3|
//   A2+CZ+A3 |BAR4| B3 |wait| C3+CZ -> probs |BAR5| sample + reg-direct out.
__global__ __launch_bounds__(256, 4) void qddpm_kernel(
    const float* __restrict__ in_re,
    const float* __restrict__ in_im,
    const float* __restrict__ params,
    const float* __restrict__ uu,
    float* __restrict__ out)
{
    __shared__ v2f   S[SPAD];          // 36 KB, interleaved (re,im), padded
    __shared__ float sprob[16];        // separate: avoids S-aliasing race

    const int b = blockIdx.x;
    const int t = threadIdx.x;
    const float uval = uu[b];

    // per-thread bases (v2f element indices)
    const int baseA = t + 2 * (t >> 4);            // A: S[baseA + 288*j], amp j*256+t
    const int baseB = (t >> 4) * 288 + (t & 15);   // B: S[baseB + 18*j],  amp (t>>4)*256+j*16+(t&15)
    const int baseC = t * 18;                      // C: S[baseC + j],     amp t*16+j (contig, 16B-aligned)

    v2f x[16];

    // ---- direct global -> registers, C-partition ----
    {
        const float4* re4 = (const float4*)(in_re + (size_t)b * DIM + t * 16);
        const float4* im4 = (const float4*)(in_im + (size_t)b * DIM + t * 16);
#pragma unroll
        for (int q = 0; q < 4; ++q) {
            const float4 vr = re4[q];
            const float4 vi = im4[q];
            x[4 * q + 0] = (v2f){vr.x, vi.x};
            x[4 * q + 1] = (v2f){vr.y, vi.y};
            x[4 * q + 2] = (v2f){vr.z, vi.z};
            x[4 * q + 3] = (v2f){vr.w, vi.w};
        }
    }

    // ---- per-wave gate coefficients: lane g (g<48) holds gate g's (cc,cs,ss,sc)
    const int lane = t & 63;
    float gv0 = 0.f, gv1 = 0.f, gv2 = 0.f, gv3 = 0.f;
    if (lane < 48) {
        const int lay = lane / 12, q = lane - lay * 12;
        float c1, s1, c2, s2;
        sincosf(params[lay * 24 + q] * 0.5f, &s1, &c1);
        sincosf(params[lay * 24 + 12 + q] * 0.5f, &s2, &c2);
        gv0 = c1 * c2; gv1 = c1 * s2; gv2 = s1 * s2; gv3 = s1 * c2;
    }

    // ---- CZ sign-bit xor words for A- and C-partition views ----
    int swA[16], swC[16];
#pragma unroll
    for (int j = 0; j < 16; ++j) {
        const int iC = t * 16 + j;
        swC[j] = (__popc(iC & (iC >> 1) & 0x7FF) & 1) << 31;
        const int iA = j * 256 + t;
        swA[j] = (__popc(iA & (iA >> 1) & 0x7FF) & 1) << 31;
    }

    // ---- P1: C gates layer0 (q8..q11); no barrier before (regs + readlane) ----
    apply4(x, gv0, gv1, gv2, gv3, 0 * 12 + 8);
    {
        float4* dst = (float4*)(S + baseC);
#pragma unroll
        for (int q = 0; q < 8; ++q)
            dst[q] = make_float4(x[2 * q].x, x[2 * q].y, x[2 * q + 1].x, x[2 * q + 1].y);
    }
    WAVEWAIT();                          // C->B is quarter-wave-local

    // ---- P2: B gates layer0 ----
#pragma unroll
    for (int j = 0; j < 16; ++j) x[j] = S[baseB + 18 * j];
    apply4(x, gv0, gv1, gv2, gv3, 0 * 12 + 4);
#pragma unroll
    for (int j = 0; j < 16; ++j) S[baseB + 18 * j] = x[j];
    __syncthreads();                     // BAR1: B->A crosses waves

    // ---- P3: A layer0 + CZ0 + A layer1 ----
#pragma unroll
    for (int j = 0; j < 16; ++j) x[j] = S[baseA + 288 * j];
    apply4(x, gv0, gv1, gv2, gv3, 0 * 12 + 0);
    applyCZ(x, swA);
    apply4(x, gv0, gv1, gv2, gv3, 1 * 12 + 0);
#pragma unroll
    for (int j = 0; j < 16; ++j) S[baseA + 288 * j] = x[j];
    __syncthreads();                     // BAR2: A->B crosses waves

    // ---- P4: B layer1 ----
#pragma unroll
    for (int j = 0; j < 16; ++j) x[j] = S[baseB + 18 * j];
    apply4(x, gv0, gv1, gv2, gv3, 1 * 12 + 4);
#pragma unroll
    for (int j = 0; j < 16; ++j) S[baseB + 18 * j] = x[j];
    WAVEWAIT();                          // B->C local

    // ---- P5: C layer1 + CZ1 + C layer2 ----
    {
        const float4* src = (const float4*)(S + baseC);
#pragma unroll
        for (int q = 0; q < 8; ++q) {
            const float4 v = src[q];
            x[2 * q]     = (v2f){v.x, v.y};
            x[2 * q + 1] = (v2f){v.z, v.w};
        }
    }
    apply4(x, gv0, gv1, gv2, gv3, 1 * 12 + 8);
    applyCZ(x, swC);
    apply4(x, gv0, gv1, gv2, gv3, 2 * 12 + 8);
    {
        float4* dst = (float4*)(S + baseC);
#pragma unroll
        for (int q = 0; q < 8; ++q)
            dst[q] = make_float4(x[2 * q].x, x[2 * q].y, x[2 * q + 1].x, x[2 * q + 1].y);
    }
    WAVEWAIT();                          // C->B local

    // ---- P6: B layer2 ----
#pragma unroll
    for (int j = 0; j < 16; ++j) x[j] = S[baseB + 18 * j];
    apply4(x, gv0, gv1, gv2, gv3, 2 * 12 + 4);
#pragma unroll
    for (int j = 0; j < 16; ++j) S[baseB + 18 * j] = x[j];
    __syncthreads();                     // BAR3: B->A

    // ---- P7: A layer2 + CZ2 + A layer3 ----
#pragma unroll
    for (int j = 0; j < 16; ++j) x[j] = S[baseA + 288 * j];
    apply4(x, gv0, gv1, gv2, gv3, 2 * 12 + 0);
    applyCZ(x, swA);
    apply4(x, gv0, gv1, gv2, gv3, 3 * 12 + 0);
#pragma unroll
    for (int j = 0; j < 16; ++j) S[baseA + 288 * j] = x[j];
    __syncthreads();                     // BAR4: A->B

    // ---- P8: B layer3 ----
#pragma unroll
    for (int j = 0; j < 16; ++j) x[j] = S[baseB + 18 * j];
    apply4(x, gv0, gv1, gv2, gv3, 3 * 12 + 4);
#pragma unroll
    for (int j = 0; j < 16; ++j) S[baseB + 18 * j] = x[j];
    WAVEWAIT();                          // B->C local

    // ---- P9: C layer3 + CZ3; state stays in registers (no S write-back) ----
    {
        const float4* src = (const float4*)(S + baseC);
#pragma unroll
        for (int q = 0; q < 8; ++q) {
            const float4 v = src[q];
            x[2 * q]     = (v2f){v.x, v.y};
            x[2 * q + 1] = (v2f){v.z, v.w};
        }
    }
    apply4(x, gv0, gv1, gv2, gv3, 3 * 12 + 8);
    applyCZ(x, swC);

    // probs: thread t's 16 amps (i = t*16+j) all belong to outcome t>>4
    {
        v2f acc2 = (v2f){0.0f, 0.0f};
#pragma unroll
        for (int j = 0; j < 16; ++j) acc2 += x[j] * x[j];
        float partial = acc2.x + acc2.y;
#pragma unroll
        for (int o = 8; o > 0; o >>= 1)
            partial += __shfl_down(partial, o, 16);
        if ((t & 15) == 0) sprob[t >> 4] = partial;
    }
    __syncthreads();                     // BAR5: sprob visible

    // ---- redundant per-thread inverse-CDF sample + register-direct output ----
    {
        float cdf[16];
        float a = 0.0f;
#pragma unroll
        for (int i = 0; i < 16; ++i) { a += sprob[i]; cdf[i] = a; }
        const float thresh = uval * a;
        int m = 0;
#pragma unroll
        for (int i = 15; i >= 0; --i) { if (cdf[i] >= thresh) m = i; }
        const float rn = 1.0f / sqrtf(sprob[m]);

        // threads with t>>4 == m hold outcome m's 256 amps in registers:
        // amp m*256 + (t&15)*16 + j  ->  out[b][(t&15)*16 + j]
        if ((t >> 4) == m) {
            float4* o = (float4*)out + (size_t)b * 128 + (t & 15) * 8;
#pragma unroll
            for (int q = 0; q < 8; ++q)
                o[q] = make_float4(x[2 * q].x * rn, x[2 * q].y * rn,
                                   x[2 * q + 1].x * rn, x[2 * q + 1].y * rn);
        }
    }
}

extern "C" void kernel_launch(void* const* d_in, const int* in_sizes, int n_in,
                              void* d_out, int out_size, void* d_ws, size_t ws_size,
                              hipStream_t stream) {
    const float* in_re  = (const float*)d_in[0];
    const float* in_im  = (const float*)d_in[1];
    const float* params = (const float*)d_in[2];
    const float* u      = (const float*)d_in[3];
    float* out = (float*)d_out;
    qddpm_kernel<<<NB, 256, 0, stream>>>(in_re, in_im, params, u, out);
}